// Round 1
// baseline (310.024 us; speedup 1.0000x reference)
//
#include <hip/hip_runtime.h>
#include <hip/hip_bf16.h>

#define B_STEPS 500000
#define HDIM 64
#define IDIM 16
#define CHUNK 128
#define WARM 32

// One wave (64 lanes) per chunk; lane j owns hidden channel j.
// Recurrence y <- sigmoid(a_t + wy*y) is contractive (|dy'/dy| <= wy/4 < 1/4),
// so a 32-step warm-up from a 0.5 guess converges to the true trajectory to
// ~1e-20 before the chunk's own steps begin. Chunk 0 starts exactly at y=0.
__global__ __launch_bounds__(64, 4)
void ANN_LeafRiver_kernel(const float* __restrict__ x,
                          const float* __restrict__ weight,
                          const float* __restrict__ weight_y,
                          const float* __restrict__ bias,
                          const float* __restrict__ weight_ln,
                          const float* __restrict__ bias_ln,
                          float* __restrict__ out)
{
    const int lane = threadIdx.x;
    const int c = blockIdx.x;
    const int t0 = c * CHUNK;
    if (t0 >= B_STEPS) return;
    const int t1 = (t0 + CHUNK < B_STEPS) ? (t0 + CHUNK) : B_STEPS;
    const int tstart = (c == 0) ? 0 : (t0 - WARM);

    // Per-lane parameters (lane j = channel j)
    float wc0  = weight[0 * HDIM + lane];
    float wc1  = weight[1 * HDIM + lane];
    float wc2  = weight[2 * HDIM + lane];
    float wc3  = weight[3 * HDIM + lane];
    float wc4  = weight[4 * HDIM + lane];
    float wc5  = weight[5 * HDIM + lane];
    float wc6  = weight[6 * HDIM + lane];
    float wc7  = weight[7 * HDIM + lane];
    float wc8  = weight[8 * HDIM + lane];
    float wc9  = weight[9 * HDIM + lane];
    float wc10 = weight[10 * HDIM + lane];
    float wc11 = weight[11 * HDIM + lane];
    float wc12 = weight[12 * HDIM + lane];
    float wc13 = weight[13 * HDIM + lane];
    float wc14 = weight[14 * HDIM + lane];
    float wc15 = weight[15 * HDIM + lane];
    const float wy  = weight_y[lane];
    const float wln = weight_ln[lane];
    const float b   = bias[0];
    const float bln = bias_ln[0];

    float y_hs = (c == 0) ? 0.0f : 0.5f;
    float y_h  = 0.0f;

    for (int t = tstart; t < t1; ++t) {
        // x[t, 0, 0:16] — wave-uniform address -> scalar loads
        const float4* xr = (const float4*)(x + (size_t)t * 64);
        float4 xa = xr[0];
        float4 xb = xr[1];
        float4 xc = xr[2];
        float4 xd = xr[3];

        float a0 = fmaf(xa.x, wc0, b);
        a0 = fmaf(xa.y, wc1, a0);
        a0 = fmaf(xa.z, wc2, a0);
        a0 = fmaf(xa.w, wc3, a0);
        float a1 = xb.x * wc4;
        a1 = fmaf(xb.y, wc5, a1);
        a1 = fmaf(xb.z, wc6, a1);
        a1 = fmaf(xb.w, wc7, a1);
        float a2 = xc.x * wc8;
        a2 = fmaf(xc.y, wc9, a2);
        a2 = fmaf(xc.z, wc10, a2);
        a2 = fmaf(xc.w, wc11, a2);
        float a3 = xd.x * wc12;
        a3 = fmaf(xd.y, wc13, a3);
        a3 = fmaf(xd.z, wc14, a3);
        a3 = fmaf(xd.w, wc15, a3);
        float a = (a0 + a1) + (a2 + a3);

        y_h = fmaf(y_hs, wy, a);
        y_hs = 1.0f / (1.0f + __expf(-y_h));

        // out[t] = bias_ln + sum_j y_hs[j]*wln[j]
        float p = y_hs * wln;
        #pragma unroll
        for (int off = 32; off > 0; off >>= 1)
            p += __shfl_xor(p, off, 64);

        if (t >= t0 && lane == 0)
            out[t] = bln + p;
    }

    if (t1 == B_STEPS) {
        out[B_STEPS + lane] = y_h;          // y_h_f
        out[B_STEPS + HDIM + lane] = y_hs;  // y_hs_f
    }
}

extern "C" void kernel_launch(void* const* d_in, const int* in_sizes, int n_in,
                              void* d_out, int out_size, void* d_ws, size_t ws_size,
                              hipStream_t stream) {
    const float* x       = (const float*)d_in[0];
    const float* weight  = (const float*)d_in[1];
    const float* wy      = (const float*)d_in[2];
    const float* bias    = (const float*)d_in[3];
    const float* wln     = (const float*)d_in[4];
    const float* bias_ln = (const float*)d_in[5];
    float* out = (float*)d_out;

    const int grid = (B_STEPS + CHUNK - 1) / CHUNK;  // 3907 chunks
    ANN_LeafRiver_kernel<<<grid, 64, 0, stream>>>(x, weight, wy, bias, wln, bias_ln, out);
}

// Round 2
// 192.568 us; speedup vs baseline: 1.6099x; 1.6099x over previous
//
#include <hip/hip_runtime.h>
#include <hip/hip_bf16.h>

#define NB 500000
#define HDIM 64
#define CHUNK 160          // 500000 = 3125 * 160, exact
#define WARM 16            // contraction <= 1/4 per step -> err <= 0.25^16 ~ 2e-10
#define NCHUNK 3125
#define BATCH 32

// One wave (64 lanes) per chunk; lane j owns hidden channel j.
// y <- sigmoid(a_t + wy*y) is contractive (|d/dy| <= wy*sigma' <= 1/4), so a
// 16-step warm-up from 0.5 converges to the true trajectory far below the
// absmax threshold. Chunk 0 starts exactly at y=0.
//
// Per 32-step batch:
//   - x rows prefetched one batch ahead into registers (coalesced float4),
//     then staged to LDS; in-loop x reads are wave-uniform LDS broadcasts.
//   - p = y_hs*wln written to ybuf (stride 65 -> conflict-free), reduced once
//     per batch with a transposed per-lane sum (1 shuffle per 32 outputs).
__global__ __launch_bounds__(64)
void ANN_LeafRiver_kernel(const float* __restrict__ x,
                          const float* __restrict__ weight,
                          const float* __restrict__ weight_y,
                          const float* __restrict__ bias,
                          const float* __restrict__ weight_ln,
                          const float* __restrict__ bias_ln,
                          float* __restrict__ out)
{
    __shared__ float xbuf[BATCH * 16];        // 2 KB: 32 rows x 16 floats
    __shared__ float ybuf[BATCH * 65];        // 8.32 KB: 32 rows x 64 (+1 pad)

    const int lane = threadIdx.x;
    const int c = blockIdx.x;
    const int t0 = c * CHUNK;

    float wc[16];
    #pragma unroll
    for (int i = 0; i < 16; ++i) wc[i] = weight[i * HDIM + lane];
    const float wy  = weight_y[lane];
    const float wln = weight_ln[lane];
    const float b   = bias[0];
    const float bln = bias_ln[0];

    float y_hs = (c == 0) ? 0.0f : 0.5f;
    float y_h  = 0.0f;

    // cooperative staging map: lane -> (row tr, 4-float column q4)
    const int tr = lane >> 2;
    const int q4 = (lane & 3) * 4;

    // stage warm-up x (16 rows, 1 float4 per lane)
    if (c != 0) {
        float4 wv = *(const float4*)(x + (size_t)(t0 - WARM + tr) * 64 + q4);
        ((float4*)xbuf)[lane] = wv;
    }
    // prefetch batch 0 (rows t0 .. t0+31) into registers
    float4 pf0 = *(const float4*)(x + (size_t)(t0 + tr) * 64 + q4);
    float4 pf1 = *(const float4*)(x + (size_t)(t0 + 16 + tr) * 64 + q4);

    __syncthreads();

    if (c != 0) {
        #pragma unroll
        for (int s = 0; s < WARM; ++s) {
            const float* xr = &xbuf[s * 16];
            float a0 = b, a1 = 0.f, a2 = 0.f, a3 = 0.f;
            #pragma unroll
            for (int i = 0; i < 4; ++i) {
                a0 = fmaf(xr[i],      wc[i],      a0);
                a1 = fmaf(xr[4 + i],  wc[4 + i],  a1);
                a2 = fmaf(xr[8 + i],  wc[8 + i],  a2);
                a3 = fmaf(xr[12 + i], wc[12 + i], a3);
            }
            const float a = (a0 + a1) + (a2 + a3);
            y_h  = fmaf(y_hs, wy, a);
            y_hs = __builtin_amdgcn_rcpf(1.0f + __expf(-y_h));
        }
    }

    int tb = t0;
    #pragma unroll 1
    for (int batch = 0; batch < CHUNK / BATCH; ++batch) {
        __syncthreads();                       // xbuf/ybuf free for reuse
        ((float4*)xbuf)[lane]      = pf0;      // rows 0..15
        ((float4*)xbuf)[64 + lane] = pf1;      // rows 16..31
        __syncthreads();                       // xbuf visible

        // prefetch next batch (latency hidden under 32 steps of compute)
        if (batch < CHUNK / BATCH - 1) {
            pf0 = *(const float4*)(x + (size_t)(tb + 32 + tr) * 64 + q4);
            pf1 = *(const float4*)(x + (size_t)(tb + 48 + tr) * 64 + q4);
        }

        #pragma unroll
        for (int s = 0; s < BATCH; ++s) {
            const float* xr = &xbuf[s * 16];   // wave-uniform -> LDS broadcast
            float a0 = b, a1 = 0.f, a2 = 0.f, a3 = 0.f;
            #pragma unroll
            for (int i = 0; i < 4; ++i) {
                a0 = fmaf(xr[i],      wc[i],      a0);
                a1 = fmaf(xr[4 + i],  wc[4 + i],  a1);
                a2 = fmaf(xr[8 + i],  wc[8 + i],  a2);
                a3 = fmaf(xr[12 + i], wc[12 + i], a3);
            }
            const float a = (a0 + a1) + (a2 + a3);
            y_h  = fmaf(y_hs, wy, a);
            y_hs = __builtin_amdgcn_rcpf(1.0f + __expf(-y_h));
            ybuf[s * 65 + lane] = y_hs * wln;  // banks (s+lane)%32: 2-way, free
        }
        __syncthreads();                       // ybuf visible

        // transposed reduction: lane (r,h) sums row r, half h
        {
            const int r = lane & 31;
            const int h = lane >> 5;
            const float* yb = &ybuf[r * 65 + h * 32];
            float p = 0.f;
            #pragma unroll
            for (int k = 0; k < 32; ++k) p += yb[k];   // banks (r+k)%32: clean
            p += __shfl_xor(p, 32, 64);
            if (lane < 32) out[tb + r] = bln + p;      // 128B coalesced
        }
        tb += BATCH;
    }

    if (c == NCHUNK - 1) {
        out[NB + lane] = y_h;            // y_h_f
        out[NB + HDIM + lane] = y_hs;    // y_hs_f
    }
}

extern "C" void kernel_launch(void* const* d_in, const int* in_sizes, int n_in,
                              void* d_out, int out_size, void* d_ws, size_t ws_size,
                              hipStream_t stream) {
    const float* x       = (const float*)d_in[0];
    const float* weight  = (const float*)d_in[1];
    const float* wy      = (const float*)d_in[2];
    const float* bias    = (const float*)d_in[3];
    const float* wln     = (const float*)d_in[4];
    const float* bias_ln = (const float*)d_in[5];
    float* out = (float*)d_out;

    ANN_LeafRiver_kernel<<<NCHUNK, 64, 0, stream>>>(x, weight, wy, bias, wln, bias_ln, out);
}

// Round 3
// 188.343 us; speedup vs baseline: 1.6461x; 1.0224x over previous
//
#include <hip/hip_runtime.h>
#include <hip/hip_bf16.h>

#define NB 500000
#define HDIM 64
#define CHUNK 80           // 500000 = 6250 * 80, exact
#define WARM 8             // contraction <= 1/4 per step -> err <= 0.5*0.25^8 ~ 8e-6
#define NCHUNK 6250
#define BATCH 16
#define NBATCH (CHUNK / BATCH)

// One wave (64 lanes) per chunk; lane j owns hidden channel j.
// y <- sigmoid(a_t + wy*y) is contractive (|d/dy| <= wy*sigma' <= 1/4), so an
// 8-step warm-up from 0.5 converges to the true trajectory far below the
// absmax threshold. Chunk 0 starts exactly at y=0.
//
// Per 16-step batch:
//   - x rows prefetched one batch ahead into registers (coalesced float4),
//     then staged to LDS; in-loop x reads are wave-uniform LDS broadcasts.
//   - p = y_hs*wln written to ybuf (stride 65 -> 2-way max, free), reduced
//     once per batch with a transposed per-lane sum (2 shuffles / 16 outputs).
// CHUNK=80 -> 6250 one-wave blocks -> ~6 waves/SIMD for latency hiding.
__global__ __launch_bounds__(64, 6)
void ANN_LeafRiver_kernel(const float* __restrict__ x,
                          const float* __restrict__ weight,
                          const float* __restrict__ weight_y,
                          const float* __restrict__ bias,
                          const float* __restrict__ weight_ln,
                          const float* __restrict__ bias_ln,
                          float* __restrict__ out)
{
    __shared__ float xbuf[BATCH * 16];        // 1 KB: 16 rows x 16 floats
    __shared__ float ybuf[BATCH * 65];        // 4.16 KB: 16 rows x 64 (+1 pad)

    const int lane = threadIdx.x;
    const int c = blockIdx.x;
    const int t0 = c * CHUNK;

    float wc[16];
    #pragma unroll
    for (int i = 0; i < 16; ++i) wc[i] = weight[i * HDIM + lane];
    const float wy  = weight_y[lane];
    const float wln = weight_ln[lane];
    const float b   = bias[0];
    const float bln = bias_ln[0];

    float y_hs = (c == 0) ? 0.0f : 0.5f;
    float y_h  = 0.0f;

    // cooperative staging map: lane -> (row lane>>2, 4-float column (lane&3)*4)
    const int tr = lane >> 2;
    const int q4 = (lane & 3) * 4;

    // stage warm-up x (8 rows, 32 lanes active)
    if (c != 0 && lane < 32) {
        float4 wv = *(const float4*)(x + (size_t)(t0 - WARM + tr) * 64 + q4);
        ((float4*)xbuf)[lane] = wv;
    }
    // prefetch batch 0 (rows t0 .. t0+15) into registers
    float4 pf = *(const float4*)(x + (size_t)(t0 + tr) * 64 + q4);

    __syncthreads();

    if (c != 0) {
        #pragma unroll
        for (int s = 0; s < WARM; ++s) {
            const float* xr = &xbuf[s * 16];
            float a0 = b, a1 = 0.f, a2 = 0.f, a3 = 0.f;
            #pragma unroll
            for (int i = 0; i < 4; ++i) {
                a0 = fmaf(xr[i],      wc[i],      a0);
                a1 = fmaf(xr[4 + i],  wc[4 + i],  a1);
                a2 = fmaf(xr[8 + i],  wc[8 + i],  a2);
                a3 = fmaf(xr[12 + i], wc[12 + i], a3);
            }
            const float a = (a0 + a1) + (a2 + a3);
            y_h  = fmaf(y_hs, wy, a);
            y_hs = __builtin_amdgcn_rcpf(1.0f + __expf(-y_h));
        }
    }

    int tb = t0;
    #pragma unroll 1
    for (int batch = 0; batch < NBATCH; ++batch) {
        __syncthreads();                       // xbuf/ybuf free for reuse
        ((float4*)xbuf)[lane] = pf;            // rows 0..15
        __syncthreads();                       // xbuf visible

        // prefetch next batch (latency hidden under 16 steps of compute)
        if (batch < NBATCH - 1) {
            pf = *(const float4*)(x + (size_t)(tb + BATCH + tr) * 64 + q4);
        }

        #pragma unroll
        for (int s = 0; s < BATCH; ++s) {
            const float* xr = &xbuf[s * 16];   // wave-uniform -> LDS broadcast
            float a0 = b, a1 = 0.f, a2 = 0.f, a3 = 0.f;
            #pragma unroll
            for (int i = 0; i < 4; ++i) {
                a0 = fmaf(xr[i],      wc[i],      a0);
                a1 = fmaf(xr[4 + i],  wc[4 + i],  a1);
                a2 = fmaf(xr[8 + i],  wc[8 + i],  a2);
                a3 = fmaf(xr[12 + i], wc[12 + i], a3);
            }
            const float a = (a0 + a1) + (a2 + a3);
            y_h  = fmaf(y_hs, wy, a);
            y_hs = __builtin_amdgcn_rcpf(1.0f + __expf(-y_h));
            ybuf[s * 65 + lane] = y_hs * wln;  // banks (s+lane)%32: 2-way, free
        }
        __syncthreads();                       // ybuf visible

        // transposed reduction: lane (r,h) sums row r, quarter h
        {
            const int r = lane & 15;
            const int h = lane >> 4;
            const float* yb = &ybuf[r * 65 + h * 16];
            float p = 0.f;
            #pragma unroll
            for (int k = 0; k < 16; ++k) p += yb[k];   // 2-way max, free
            p += __shfl_xor(p, 16, 64);
            p += __shfl_xor(p, 32, 64);
            if (lane < 16) out[tb + r] = bln + p;      // 64B coalesced
        }
        tb += BATCH;
    }

    if (c == NCHUNK - 1) {
        out[NB + lane] = y_h;            // y_h_f
        out[NB + HDIM + lane] = y_hs;    // y_hs_f
    }
}

extern "C" void kernel_launch(void* const* d_in, const int* in_sizes, int n_in,
                              void* d_out, int out_size, void* d_ws, size_t ws_size,
                              hipStream_t stream) {
    const float* x       = (const float*)d_in[0];
    const float* weight  = (const float*)d_in[1];
    const float* wy      = (const float*)d_in[2];
    const float* bias    = (const float*)d_in[3];
    const float* wln     = (const float*)d_in[4];
    const float* bias_ln = (const float*)d_in[5];
    float* out = (float*)d_out;

    ANN_LeafRiver_kernel<<<NCHUNK, 64, 0, stream>>>(x, weight, wy, bias, wln, bias_ln, out);
}

// Round 4
// 184.501 us; speedup vs baseline: 1.6803x; 1.0208x over previous
//
#include <hip/hip_runtime.h>

#define NB     500000
#define HDIM   64
#define BATCH  32
#define CHUNK  96          // 5208 full chunks of 96 + one tail chunk of 32 = 500000
#define NFULL  5208
#define NCHUNK 5209
#define WARM   8           // contraction <= 1/4 per step -> warm error ~ 1.5e-5
#define LDP    65          // LDS leading dim: 64 + 1 pad -> conflict-free

typedef _Float16 v8h  __attribute__((ext_vector_type(8)));
typedef float    v16f __attribute__((ext_vector_type(16)));

// One wave per chunk; lane j owns hidden channel j in the sequential phase.
// Per 32-step batch the x@W projection (M=32 steps, K=16, N=64) is done by two
// v_mfma_f32_32x32x16_f16 (bias pre-loaded in the C operand), D staged through
// padded LDS to transpose MFMA C-layout -> lane=channel, then the serial
// sigmoid recurrence runs at ~8 instr/step instead of ~24.
// A-frag: lane holds x[tb + (lane&31)][k0..k0+7], k0=(lane>>5)*8.
// B-frag: lane holds W[k0..k0+7][(lane&31) + 32*tile]. Shared k-order between
// A and B makes the result invariant to the exact k permutation.
// C/D (verified m74/m101): col=lane&31, row=(reg&3)+8*(reg>>2)+4*(lane>>5).
__global__ __launch_bounds__(64)
void ANN_LeafRiver_kernel(const float* __restrict__ x,
                          const float* __restrict__ weight,
                          const float* __restrict__ weight_y,
                          const float* __restrict__ bias,
                          const float* __restrict__ weight_ln,
                          const float* __restrict__ bias_ln,
                          float* __restrict__ out)
{
    __shared__ float buf[BATCH * LDP];   // 8.32 KB

    const int lane = threadIdx.x;
    const int c    = blockIdx.x;
    const int t0   = c * CHUNK;
    const int half = lane >> 5;          // k-block (A/B) and row-half (C/D)
    const int l31  = lane & 31;
    const int k0   = half * 8;

    // B fragments (loaded once; RNE casts)
    v8h bf0, bf1;
    #pragma unroll
    for (int j = 0; j < 8; ++j) {
        bf0[j] = (_Float16)weight[(k0 + j) * HDIM + l31];
        bf1[j] = (_Float16)weight[(k0 + j) * HDIM + l31 + 32];
    }
    const float wy  = weight_y[lane];
    const float wln = weight_ln[lane];
    const float b   = bias[0];
    const float bln = bias_ln[0];

    v16f cb;                              // bias folded into MFMA C operand
    #pragma unroll
    for (int r = 0; r < 16; ++r) cb[r] = b;

    float y_hs = (c == 0) ? 0.0f : 0.5f;
    float y_h  = 0.0f;

    float* wb = &buf[half * 4 * LDP + l31];   // D-write base for this lane

    // ---- warm-up: one MFMA batch at t0-8, consume only rows 0..7 ----
    if (c != 0) {
        const float* xp = x + (size_t)(t0 - WARM + l31) * 64 + k0;
        float4 lo = *(const float4*)xp;
        float4 hi = *(const float4*)(xp + 4);
        v8h af;
        af[0] = (_Float16)lo.x; af[1] = (_Float16)lo.y;
        af[2] = (_Float16)lo.z; af[3] = (_Float16)lo.w;
        af[4] = (_Float16)hi.x; af[5] = (_Float16)hi.y;
        af[6] = (_Float16)hi.z; af[7] = (_Float16)hi.w;
        v16f d0 = __builtin_amdgcn_mfma_f32_32x32x16_f16(af, bf0, cb, 0, 0, 0);
        v16f d1 = __builtin_amdgcn_mfma_f32_32x32x16_f16(af, bf1, cb, 0, 0, 0);
        #pragma unroll
        for (int r = 0; r < 16; ++r) {
            const int off = ((r & 3) + 8 * (r >> 2)) * LDP;
            wb[off]      = d0[r];
            wb[off + 32] = d1[r];
        }
        __syncthreads();
        #pragma unroll
        for (int s = 0; s < WARM; ++s) {
            const float a = buf[s * LDP + lane];
            y_h  = fmaf(y_hs, wy, a);
            y_hs = __builtin_amdgcn_rcpf(1.0f + __expf(-y_h));
        }
        __syncthreads();
    }

    const int nb = (c == NFULL) ? 1 : (CHUNK / BATCH);
    for (int i = 0; i < nb; ++i) {
        const int tb = t0 + i * BATCH;

        // A fragment: 8 contiguous floats of x row (tb + l31)
        const float* xp = x + (size_t)(tb + l31) * 64 + k0;
        float4 lo = *(const float4*)xp;
        float4 hi = *(const float4*)(xp + 4);
        v8h af;
        af[0] = (_Float16)lo.x; af[1] = (_Float16)lo.y;
        af[2] = (_Float16)lo.z; af[3] = (_Float16)lo.w;
        af[4] = (_Float16)hi.x; af[5] = (_Float16)hi.y;
        af[6] = (_Float16)hi.z; af[7] = (_Float16)hi.w;

        v16f d0 = __builtin_amdgcn_mfma_f32_32x32x16_f16(af, bf0, cb, 0, 0, 0);
        v16f d1 = __builtin_amdgcn_mfma_f32_32x32x16_f16(af, bf1, cb, 0, 0, 0);

        // D -> LDS: a[step][channel], banks (row+col)%32 distinct per half
        #pragma unroll
        for (int r = 0; r < 16; ++r) {
            const int off = ((r & 3) + 8 * (r >> 2)) * LDP;
            wb[off]      = d0[r];
            wb[off + 32] = d1[r];
        }
        __syncthreads();

        // sequential recurrence: lane = channel; in-place overwrite with p
        #pragma unroll
        for (int s = 0; s < BATCH; ++s) {
            const float a = buf[s * LDP + lane];
            y_h  = fmaf(y_hs, wy, a);
            y_hs = __builtin_amdgcn_rcpf(1.0f + __expf(-y_h));
            buf[s * LDP + lane] = y_hs * wln;   // same slot just read by this lane
        }
        __syncthreads();

        // transposed reduction: lane (r=l31, h=half) sums row r, half h
        {
            const float* rb = &buf[l31 * LDP + half * 32];
            float p = 0.0f;
            #pragma unroll
            for (int k = 0; k < 32; ++k) p += rb[k];   // 2-way max -> free
            p += __shfl_xor(p, 32, 64);
            if (lane < 32) out[tb + l31] = bln + p;    // 128B coalesced
        }
        __syncthreads();
    }

    if (c == NCHUNK - 1) {
        out[NB + lane]        = y_h;    // y_h_f  (last step = 499999)
        out[NB + HDIM + lane] = y_hs;   // y_hs_f
    }
}

extern "C" void kernel_launch(void* const* d_in, const int* in_sizes, int n_in,
                              void* d_out, int out_size, void* d_ws, size_t ws_size,
                              hipStream_t stream) {
    const float* x       = (const float*)d_in[0];
    const float* weight  = (const float*)d_in[1];
    const float* wy      = (const float*)d_in[2];
    const float* bias    = (const float*)d_in[3];
    const float* wln     = (const float*)d_in[4];
    const float* bias_ln = (const float*)d_in[5];
    float* out = (float*)d_out;

    ANN_LeafRiver_kernel<<<NCHUNK, 64, 0, stream>>>(x, weight, wy, bias, wln, bias_ln, out);
}

// Round 6
// 181.438 us; speedup vs baseline: 1.7087x; 1.0169x over previous
//
#include <hip/hip_runtime.h>

#define NB      500000
#define HDIM    64
#define OUTC    88            // outputs per chunk
#define NCHUNK  5682          // ceil(NB/OUTC); last chunk outputs 72
#define LDP     65            // padded LDS leading dim -> conflict-free
#define NLOG2E  (-1.4426950408889634f)
#define NLN2    (-0.6931471805599453f)

typedef _Float16 half_t;
typedef half_t v8h  __attribute__((ext_vector_type(8)));
typedef float  v16f __attribute__((ext_vector_type(16)));

// One wave per chunk; lane j owns hidden channel j in the serial phase.
// Chunk covers serial steps [c*88-8, c*88+88): 8 warm-up (contraction <= 1/4
// per step -> warm error ~1.5e-5) + 88 outputs, as exactly 3 MFMA batches of
// 32 (no dedicated warm-up batch). Chunk 0 skips the warm steps (exact init).
// B/C operands pre-scaled by -log2e so the serial step needs no extra mul:
//   targ = fma(y_hs, -log2e*wy, a2);  y_hs = rcp(1 + exp2(targ))
// y_h recovered as targ * (-ln2) for the final-state output.
// A-frag: lane holds x[row=tb+(lane&31)][k0..k0+7], k0=(lane>>5)*8.
// B-frag: lane holds Ws[k0..k0+7][(lane&31)+32*tile] (shared k-order with A).
// C/D (verified m74/m101): col=lane&31, row=(r&3)+8*(r>>2)+4*(lane>>5).
__global__ __launch_bounds__(64)
void ANN_LeafRiver_kernel(const float* __restrict__ x,
                          const float* __restrict__ weight,
                          const float* __restrict__ weight_y,
                          const float* __restrict__ bias,
                          const float* __restrict__ weight_ln,
                          const float* __restrict__ bias_ln,
                          float* __restrict__ out)
{
    __shared__ float buf[32 * LDP];      // 8.32 KB

    const int lane = threadIdx.x;
    const int c    = blockIdx.x;
    const long base = (long)c * OUTC - 8;    // first serial row of this chunk
    const int half = lane >> 5;
    const int l31  = lane & 31;
    const int k0   = half * 8;

    // B fragments scaled by -log2e
    v8h bf0, bf1;
    #pragma unroll
    for (int j = 0; j < 8; ++j) {
        bf0[j] = (half_t)(weight[(k0 + j) * HDIM + l31]      * NLOG2E);
        bf1[j] = (half_t)(weight[(k0 + j) * HDIM + l31 + 32] * NLOG2E);
    }
    const float wy2 = weight_y[lane] * NLOG2E;
    const float wln = weight_ln[lane];
    const float bln = bias_ln[0];

    v16f cb;                              // scaled bias in the C operand
    {
        const float bsc = bias[0] * NLOG2E;
        #pragma unroll
        for (int r = 0; r < 16; ++r) cb[r] = bsc;
    }

    float y_hs = (c == 0) ? 0.0f : 0.5f;
    float targ = 0.0f;

    float* wb = &buf[(half * 4) * LDP + l31];   // D-write base

    // helper: load A rows (clamped) for batch bi
    auto loadA = [&](int bi, float4& lo, float4& hi) {
        long t = base + (long)bi * 32 + l31;
        if (t < 0) t = 0;
        if (t >= NB) t = NB - 1;
        const float* xp = x + t * 64 + k0;
        lo = *(const float4*)xp;
        hi = *(const float4*)(xp + 4);
    };

    float4 lo, hi;
    loadA(0, lo, hi);

    #pragma unroll
    for (int bi = 0; bi < 3; ++bi) {
        const long tb = base + bi * 32;

        // pack A fragment (RNE scalar casts -> v_cvt_f16_f32)
        v8h af;
        af[0] = (half_t)lo.x; af[1] = (half_t)lo.y;
        af[2] = (half_t)lo.z; af[3] = (half_t)lo.w;
        af[4] = (half_t)hi.x; af[5] = (half_t)hi.y;
        af[6] = (half_t)hi.z; af[7] = (half_t)hi.w;

        v16f d0 = __builtin_amdgcn_mfma_f32_32x32x16_f16(af, bf0, cb, 0, 0, 0);
        v16f d1 = __builtin_amdgcn_mfma_f32_32x32x16_f16(af, bf1, cb, 0, 0, 0);

        // D -> LDS (a2[step][channel]); imm-offset ds_writes off one base reg
        #pragma unroll
        for (int r = 0; r < 16; ++r) {
            const int off = ((r & 3) + 8 * (r >> 2)) * LDP;
            wb[off]      = d0[r];
            wb[off + 32] = d1[r];
        }

        // prefetch next batch's A rows: ~950 cyc of serial work covers HBM
        if (bi < 2) loadA(bi + 1, lo, hi);

        __syncthreads();

        // ---- serial recurrence (lane = channel) ----
        if (bi == 0) {
            if (c != 0) {
                #pragma unroll
                for (int s = 0; s < 8; ++s) {          // warm-up: no p-write
                    const float a2 = buf[s * LDP + lane];
                    targ = fmaf(y_hs, wy2, a2);
                    y_hs = __builtin_amdgcn_rcpf(1.0f + __builtin_exp2f(targ));
                }
            }
            #pragma unroll
            for (int s = 8; s < 32; ++s) {
                const float a2 = buf[s * LDP + lane];
                targ = fmaf(y_hs, wy2, a2);
                y_hs = __builtin_amdgcn_rcpf(1.0f + __builtin_exp2f(targ));
                buf[s * LDP + lane] = y_hs * wln;
            }
        } else if (tb + 32 <= NB) {
            #pragma unroll
            for (int s = 0; s < 32; ++s) {
                const float a2 = buf[s * LDP + lane];
                targ = fmaf(y_hs, wy2, a2);
                y_hs = __builtin_amdgcn_rcpf(1.0f + __builtin_exp2f(targ));
                buf[s * LDP + lane] = y_hs * wln;
            }
        } else {                                        // tail (1 chunk only)
            const int send = (int)(NB - tb);
            for (int s = 0; s < send; ++s) {
                const float a2 = buf[s * LDP + lane];
                targ = fmaf(y_hs, wy2, a2);
                y_hs = __builtin_amdgcn_rcpf(1.0f + __builtin_exp2f(targ));
                buf[s * LDP + lane] = y_hs * wln;
            }
        }
        __syncthreads();

        // ---- batched transposed reduction: lane (r=l31, h=half) ----
        {
            const float* rb = &buf[l31 * LDP + half * 32];
            float p = 0.0f;
            #pragma unroll
            for (int k = 0; k < 32; ++k) p += rb[k];    // conflict-free
            p += __shfl_xor(p, 32, 64);
            const long t = tb + l31;
            if (lane < 32 && t < NB && (bi > 0 || l31 >= 8))
                out[t] = bln + p;
        }
        __syncthreads();
    }

    if (c == NCHUNK - 1) {
        out[NB + lane]        = targ * NLN2;   // y_h_f  (t = 499999)
        out[NB + HDIM + lane] = y_hs;          // y_hs_f
    }
}

extern "C" void kernel_launch(void* const* d_in, const int* in_sizes, int n_in,
                              void* d_out, int out_size, void* d_ws, size_t ws_size,
                              hipStream_t stream) {
    const float* x       = (const float*)d_in[0];
    const float* weight  = (const float*)d_in[1];
    const float* wy      = (const float*)d_in[2];
    const float* bias    = (const float*)d_in[3];
    const float* wln     = (const float*)d_in[4];
    const float* bias_ln = (const float*)d_in[5];
    float* out = (float*)d_out;

    ANN_LeafRiver_kernel<<<NCHUNK, 64, 0, stream>>>(x, weight, wy, bias, wln, bias_ln, out);
}